// Round 1
// baseline (1268.387 us; speedup 1.0000x reference)
//
#include <hip/hip_runtime.h>
#include <hip/hip_bf16.h>

#define N_NODES_C 100000
#define N_EDGES_C 1600000
#define HID_C 128
#define NCLS_C 16
#define NGRAPH_C 512
#define SCAN_BLK 1024
#define NCHUNK ((N_NODES_C + SCAN_BLK - 1) / SCAN_BLK)  // 98

// ---------------- degree count ----------------
__global__ void k_count(const int* __restrict__ src, const int* __restrict__ dst,
                        int* cnt_out, int* cnt_in) {
  int i = blockIdx.x * blockDim.x + threadIdx.x;
  int stride = gridDim.x * blockDim.x;
  for (; i < N_EDGES_C; i += stride) {
    atomicAdd(&cnt_out[src[i]], 1);
    atomicAdd(&cnt_in[dst[i]], 1);
  }
}

__global__ void k_norm(const int* __restrict__ cnt_out, const int* __restrict__ cnt_in,
                       float* norm_src, float* norm_dst) {
  int i = blockIdx.x * blockDim.x + threadIdx.x;
  if (i < N_NODES_C) {
    norm_src[i] = 1.f / sqrtf(fmaxf((float)cnt_out[i], 1.f));
    norm_dst[i] = 1.f / sqrtf(fmaxf((float)cnt_in[i], 1.f));
  }
}

// ---------------- 3-phase exclusive scan of in-degree -> CSR row offsets ----------------
__global__ void k_scan1(const int* __restrict__ cnt, int* part) {
  __shared__ int s[SCAN_BLK];
  int tid = threadIdx.x;
  int i = blockIdx.x * SCAN_BLK + tid;
  s[tid] = (i < N_NODES_C) ? cnt[i] : 0;
  __syncthreads();
  for (int off = SCAN_BLK / 2; off > 0; off >>= 1) {
    if (tid < off) s[tid] += s[tid + off];
    __syncthreads();
  }
  if (tid == 0) part[blockIdx.x] = s[0];
}

__global__ void k_scan2(int* part, int* row_start) {
  if (threadIdx.x == 0 && blockIdx.x == 0) {
    int run = 0;
    for (int i = 0; i < NCHUNK; ++i) { int v = part[i]; part[i] = run; run += v; }
    row_start[N_NODES_C] = run;
  }
}

__global__ void k_scan3(const int* __restrict__ cnt, const int* __restrict__ part,
                        int* row_start, int* cursor) {
  __shared__ int s[SCAN_BLK];
  int tid = threadIdx.x;
  int i = blockIdx.x * SCAN_BLK + tid;
  int x = (i < N_NODES_C) ? cnt[i] : 0;
  s[tid] = x;
  __syncthreads();
  for (int off = 1; off < SCAN_BLK; off <<= 1) {
    int v = (tid >= off) ? s[tid - off] : 0;
    __syncthreads();
    s[tid] += v;
    __syncthreads();
  }
  if (i < N_NODES_C) {
    int excl = part[blockIdx.x] + s[tid] - x;
    row_start[i] = excl;
    cursor[i] = excl;
  }
}

__global__ void k_fill(const int* __restrict__ src, const int* __restrict__ dst,
                       int* cursor, int* __restrict__ csr_src) {
  int i = blockIdx.x * blockDim.x + threadIdx.x;
  int stride = gridDim.x * blockDim.x;
  for (; i < N_EDGES_C; i += stride) {
    int p = atomicAdd(&cursor[dst[i]], 1);
    csr_src[p] = src[i];
  }
}

// ---------------- GEMM: T[m][c] = (sum_k A[m][k] W[k][c]) * rowscale[m] ----------------
// f32 vector GEMM (no fp32 MFMA on CDNA4). 256 thr, tile 128x128, 8x8 micro-tile.
__global__ __launch_bounds__(256) void k_gemm_rowscale(
    const float* __restrict__ A, const float* __restrict__ W,
    const float* __restrict__ rowscale, float* __restrict__ T, int rows) {
  __shared__ float sA[32][132];  // [k][m], pad 4 -> 16B-aligned row stride
  __shared__ float sB[32][132];  // [k][n]
  int t = threadIdx.x;
  int tx = t & 15, ty = t >> 4;
  int m0 = blockIdx.x * 128;

  float acc[8][8];
#pragma unroll
  for (int i = 0; i < 8; ++i)
#pragma unroll
    for (int j = 0; j < 8; ++j) acc[i][j] = 0.f;

  for (int k0 = 0; k0 < HID_C; k0 += 32) {
    // stage A chunk: 128 rows x 32 k (transposed into LDS)
    int c = t & 31, r0 = t >> 5;  // r0: 0..7
#pragma unroll
    for (int rr = 0; rr < 16; ++rr) {
      int r = rr * 8 + r0;
      int row = m0 + r;
      float v = (row < rows) ? A[(size_t)row * HID_C + k0 + c] : 0.f;
      sA[c][r] = v;
    }
    // stage W chunk: 32 k x 128 n
#pragma unroll
    for (int i = 0; i < 16; ++i) {
      int idx = t + i * 256;
      int kc = idx >> 7, n = idx & 127;
      sB[kc][n] = W[(size_t)(k0 + kc) * HID_C + n];
    }
    __syncthreads();

#pragma unroll 8
    for (int kk = 0; kk < 32; ++kk) {
      float a[8], b[8];
#pragma unroll
      for (int i = 0; i < 8; ++i) a[i] = sA[kk][ty * 8 + i];
#pragma unroll
      for (int j = 0; j < 8; ++j) b[j] = sB[kk][tx * 8 + j];
#pragma unroll
      for (int i = 0; i < 8; ++i)
#pragma unroll
        for (int j = 0; j < 8; ++j) acc[i][j] = fmaf(a[i], b[j], acc[i][j]);
    }
    __syncthreads();
  }

#pragma unroll
  for (int i = 0; i < 8; ++i) {
    int row = m0 + ty * 8 + i;
    if (row < rows) {
      float sc = rowscale[row];
      float4 v0 = {acc[i][0] * sc, acc[i][1] * sc, acc[i][2] * sc, acc[i][3] * sc};
      float4 v1 = {acc[i][4] * sc, acc[i][5] * sc, acc[i][6] * sc, acc[i][7] * sc};
      float4* p = (float4*)&T[(size_t)row * HID_C + tx * 8];
      p[0] = v0;
      p[1] = v1;
    }
  }
}

// ---------------- aggregation: H[n] = relu(norm_dst[n] * sum_{e: dst=n} T[src[e]] + b) ----------------
__global__ __launch_bounds__(256) void k_agg(
    const float* __restrict__ T, const int* __restrict__ row_start,
    const int* __restrict__ csr_src, const float* __restrict__ norm_dst,
    const float* __restrict__ bias, float* __restrict__ H) {
  int wid = threadIdx.x >> 6, lane = threadIdx.x & 63;
  int n = blockIdx.x * 4 + wid;
  if (n >= N_NODES_C) return;
  int s0 = row_start[n], s1 = row_start[n + 1];
  const float2* T2 = (const float2*)T;
  float ax = 0.f, ay = 0.f;
  for (int base = s0; base < s1; base += 64) {
    int m = s1 - base;
    if (m > 64) m = 64;
    int idx = (lane < m) ? csr_src[base + lane] : 0;
    int j = 0;
    for (; j + 4 <= m; j += 4) {
      int a0 = __shfl(idx, j), a1 = __shfl(idx, j + 1);
      int a2 = __shfl(idx, j + 2), a3 = __shfl(idx, j + 3);
      float2 v0 = T2[(size_t)a0 * 64 + lane];
      float2 v1 = T2[(size_t)a1 * 64 + lane];
      float2 v2 = T2[(size_t)a2 * 64 + lane];
      float2 v3 = T2[(size_t)a3 * 64 + lane];
      ax += v0.x + v1.x + v2.x + v3.x;
      ay += v0.y + v1.y + v2.y + v3.y;
    }
    for (; j < m; ++j) {
      int a = __shfl(idx, j);
      float2 v = T2[(size_t)a * 64 + lane];
      ax += v.x;
      ay += v.y;
    }
  }
  float nd = norm_dst[n];
  float bx = bias[2 * lane], by = bias[2 * lane + 1];
  float2 r;
  r.x = fmaxf(fmaf(ax, nd, bx), 0.f);
  r.y = fmaxf(fmaf(ay, nd, by), 0.f);
  ((float2*)H)[(size_t)n * 64 + lane] = r;
}

// ---------------- readout 1: w = sigmoid(h.Wv + bv); num[g] += h*w; den[g] += w ----------------
__global__ __launch_bounds__(256) void k_readout1(
    const float* __restrict__ H, const float* __restrict__ Wv, const float* __restrict__ bv,
    const int* __restrict__ gid, float* num, float* den) {
  int wid = threadIdx.x >> 6, lane = threadIdx.x & 63;
  int n = blockIdx.x * 4 + wid;
  if (n >= N_NODES_C) return;
  float2 h2 = ((const float2*)H)[(size_t)n * 64 + lane];
  float2 wv2 = ((const float2*)Wv)[lane];
  float p = h2.x * wv2.x + h2.y * wv2.y;
#pragma unroll
  for (int off = 32; off > 0; off >>= 1) p += __shfl_xor(p, off);
  float w = 1.f / (1.f + expf(-(p + bv[0])));
  int g = gid[n];
  atomicAdd(&num[g * HID_C + 2 * lane], h2.x * w);
  atomicAdd(&num[g * HID_C + 2 * lane + 1], h2.y * w);
  if (lane == 0) atomicAdd(&den[g], w);
}

// ---------------- readout 2: out[g][c] = (sum_k num[g][k] Wc[k][c]) / den[g] + bc[c] ----------------
__global__ void k_readout2(const float* __restrict__ num, const float* __restrict__ den,
                           const float* __restrict__ Wc, const float* __restrict__ bc,
                           float* __restrict__ out) {
  int t = blockIdx.x * blockDim.x + threadIdx.x;
  if (t >= NGRAPH_C * NCLS_C) return;
  int g = t / NCLS_C, c = t % NCLS_C;
  float d = den[g];
  float inv = (d > 0.f) ? 1.f / d : 0.f;
  float acc = 0.f;
  for (int k = 0; k < HID_C; ++k) acc = fmaf(num[g * HID_C + k], Wc[k * NCLS_C + c], acc);
  out[t] = acc * inv + bc[c];
}

extern "C" void kernel_launch(void* const* d_in, const int* in_sizes, int n_in,
                              void* d_out, int out_size, void* d_ws, size_t ws_size,
                              hipStream_t stream) {
  const float* x = (const float*)d_in[0];
  const int* src = (const int*)d_in[1];
  const int* dst = (const int*)d_in[2];
  const int* gid = (const int*)d_in[3];
  const float* W[4] = {(const float*)d_in[4], (const float*)d_in[6],
                       (const float*)d_in[8], (const float*)d_in[10]};
  const float* b[4] = {(const float*)d_in[5], (const float*)d_in[7],
                       (const float*)d_in[9], (const float*)d_in[11]};
  const float* Wv = (const float*)d_in[12];
  const float* bv = (const float*)d_in[13];
  const float* Wc = (const float*)d_in[14];
  const float* bc = (const float*)d_in[15];
  float* out = (float*)d_out;

  char* ws = (char*)d_ws;
  size_t off = 0;
  auto alloc = [&](size_t bytes) -> char* {
    char* p = ws + off;
    off = (off + bytes + 255) & ~(size_t)255;
    return p;
  };
  int* cnt_out = (int*)alloc((size_t)N_NODES_C * 4);
  int* cnt_in = (int*)alloc((size_t)N_NODES_C * 4);
  float* norm_src = (float*)alloc((size_t)N_NODES_C * 4);
  float* norm_dst = (float*)alloc((size_t)N_NODES_C * 4);
  int* row_start = (int*)alloc((size_t)(N_NODES_C + 1) * 4);
  int* cursor = (int*)alloc((size_t)N_NODES_C * 4);
  int* part = (int*)alloc((size_t)SCAN_BLK * 4);
  int* csr_src = (int*)alloc((size_t)N_EDGES_C * 4);
  float* tbuf = (float*)alloc((size_t)N_NODES_C * HID_C * 4);
  float* hbuf = (float*)alloc((size_t)N_NODES_C * HID_C * 4);
  float* num = (float*)alloc((size_t)NGRAPH_C * HID_C * 4);
  float* den = (float*)alloc((size_t)NGRAPH_C * 4);
  (void)ws_size;
  (void)in_sizes;
  (void)n_in;
  (void)out_size;

  hipMemsetAsync(cnt_out, 0, (size_t)N_NODES_C * 4, stream);
  hipMemsetAsync(cnt_in, 0, (size_t)N_NODES_C * 4, stream);
  hipMemsetAsync(num, 0, (size_t)NGRAPH_C * HID_C * 4, stream);
  hipMemsetAsync(den, 0, (size_t)NGRAPH_C * 4, stream);

  k_count<<<2048, 256, 0, stream>>>(src, dst, cnt_out, cnt_in);
  k_norm<<<(N_NODES_C + 255) / 256, 256, 0, stream>>>(cnt_out, cnt_in, norm_src, norm_dst);
  k_scan1<<<NCHUNK, SCAN_BLK, 0, stream>>>(cnt_in, part);
  k_scan2<<<1, 1, 0, stream>>>(part, row_start);
  k_scan3<<<NCHUNK, SCAN_BLK, 0, stream>>>(cnt_in, part, row_start, cursor);
  k_fill<<<2048, 256, 0, stream>>>(src, dst, cursor, csr_src);

  int gemm_grid = (N_NODES_C + 127) / 128;
  int node_grid = (N_NODES_C + 3) / 4;
  const float* hin = x;
  for (int l = 0; l < 4; ++l) {
    k_gemm_rowscale<<<gemm_grid, 256, 0, stream>>>(hin, W[l], norm_src, tbuf, N_NODES_C);
    k_agg<<<node_grid, 256, 0, stream>>>(tbuf, row_start, csr_src, norm_dst, b[l], hbuf);
    hin = hbuf;
  }

  k_readout1<<<node_grid, 256, 0, stream>>>(hbuf, Wv, bv, gid, num, den);
  k_readout2<<<(NGRAPH_C * NCLS_C + 255) / 256, 256, 0, stream>>>(num, den, Wc, bc, out);
}

// Round 2
// 1057.189 us; speedup vs baseline: 1.1998x; 1.1998x over previous
//
#include <hip/hip_runtime.h>
#include <hip/hip_bf16.h>

#define N_NODES_C 100000
#define N_EDGES_C 1600000
#define HID_C 128
#define NCLS_C 16
#define NGRAPH_C 512
#define SCAN_BLK 1024
#define NCHUNK ((N_NODES_C + SCAN_BLK - 1) / SCAN_BLK)  // 98

// ---------------- degree count ----------------
__global__ void k_count(const int* __restrict__ src, const int* __restrict__ dst,
                        int* cnt_out, int* cnt_in) {
  int i = blockIdx.x * blockDim.x + threadIdx.x;
  int stride = gridDim.x * blockDim.x;
  for (; i < N_EDGES_C; i += stride) {
    atomicAdd(&cnt_out[src[i]], 1);
    atomicAdd(&cnt_in[dst[i]], 1);
  }
}

__global__ void k_norm(const int* __restrict__ cnt_out, const int* __restrict__ cnt_in,
                       float* norm_src, float* norm_dst) {
  int i = blockIdx.x * blockDim.x + threadIdx.x;
  if (i < N_NODES_C) {
    norm_src[i] = 1.f / sqrtf(fmaxf((float)cnt_out[i], 1.f));
    norm_dst[i] = 1.f / sqrtf(fmaxf((float)cnt_in[i], 1.f));
  }
}

// ---------------- 3-phase exclusive scan of in-degree -> CSR row offsets ----------------
__global__ void k_scan1(const int* __restrict__ cnt, int* part) {
  __shared__ int s[SCAN_BLK];
  int tid = threadIdx.x;
  int i = blockIdx.x * SCAN_BLK + tid;
  s[tid] = (i < N_NODES_C) ? cnt[i] : 0;
  __syncthreads();
  for (int off = SCAN_BLK / 2; off > 0; off >>= 1) {
    if (tid < off) s[tid] += s[tid + off];
    __syncthreads();
  }
  if (tid == 0) part[blockIdx.x] = s[0];
}

__global__ void k_scan2(int* part, int* row_start) {
  if (threadIdx.x == 0 && blockIdx.x == 0) {
    int run = 0;
    for (int i = 0; i < NCHUNK; ++i) { int v = part[i]; part[i] = run; run += v; }
    row_start[N_NODES_C] = run;
  }
}

__global__ void k_scan3(const int* __restrict__ cnt, const int* __restrict__ part,
                        int* row_start, int* cursor) {
  __shared__ int s[SCAN_BLK];
  int tid = threadIdx.x;
  int i = blockIdx.x * SCAN_BLK + tid;
  int x = (i < N_NODES_C) ? cnt[i] : 0;
  s[tid] = x;
  __syncthreads();
  for (int off = 1; off < SCAN_BLK; off <<= 1) {
    int v = (tid >= off) ? s[tid - off] : 0;
    __syncthreads();
    s[tid] += v;
    __syncthreads();
  }
  if (i < N_NODES_C) {
    int excl = part[blockIdx.x] + s[tid] - x;
    row_start[i] = excl;
    cursor[i] = excl;
  }
}

__global__ void k_fill(const int* __restrict__ src, const int* __restrict__ dst,
                       int* cursor, int* __restrict__ csr_src) {
  int i = blockIdx.x * blockDim.x + threadIdx.x;
  int stride = gridDim.x * blockDim.x;
  for (; i < N_EDGES_C; i += stride) {
    int p = atomicAdd(&cursor[dst[i]], 1);
    csr_src[p] = src[i];
  }
}

// ---------------- graph boundary offsets from sorted gid ----------------
__global__ void k_gstart(const int* __restrict__ gid, int* __restrict__ gstart) {
  int n = blockIdx.x * blockDim.x + threadIdx.x;
  if (n >= N_NODES_C) return;
  int g = gid[n];
  int gp = (n == 0) ? -1 : gid[n - 1];
  for (int k = gp + 1; k <= g; ++k) gstart[k] = n;
  if (n == N_NODES_C - 1) {
    for (int k = g + 1; k <= NGRAPH_C; ++k) gstart[k] = N_NODES_C;
  }
}

// ---------------- GEMM: T[m][c] = (sum_k A[m][k] W[k][c]) * rowscale[m] ----------------
// f32 vector GEMM (no fp32 MFMA on CDNA4). 256 thr, tile 128x128, 8x8 micro-tile.
__global__ __launch_bounds__(256) void k_gemm_rowscale(
    const float* __restrict__ A, const float* __restrict__ W,
    const float* __restrict__ rowscale, float* __restrict__ T, int rows) {
  __shared__ float sA[32][132];  // [k][m], pad 4 -> 16B-aligned row stride
  __shared__ float sB[32][132];  // [k][n]
  int t = threadIdx.x;
  int tx = t & 15, ty = t >> 4;
  int m0 = blockIdx.x * 128;

  float acc[8][8];
#pragma unroll
  for (int i = 0; i < 8; ++i)
#pragma unroll
    for (int j = 0; j < 8; ++j) acc[i][j] = 0.f;

  for (int k0 = 0; k0 < HID_C; k0 += 32) {
    // stage A chunk: 128 rows x 32 k (transposed into LDS)
    int c = t & 31, r0 = t >> 5;  // r0: 0..7
#pragma unroll
    for (int rr = 0; rr < 16; ++rr) {
      int r = rr * 8 + r0;
      int row = m0 + r;
      float v = (row < rows) ? A[(size_t)row * HID_C + k0 + c] : 0.f;
      sA[c][r] = v;
    }
    // stage W chunk: 32 k x 128 n
#pragma unroll
    for (int i = 0; i < 16; ++i) {
      int idx = t + i * 256;
      int kc = idx >> 7, n = idx & 127;
      sB[kc][n] = W[(size_t)(k0 + kc) * HID_C + n];
    }
    __syncthreads();

#pragma unroll 8
    for (int kk = 0; kk < 32; ++kk) {
      float a[8], b[8];
#pragma unroll
      for (int i = 0; i < 8; ++i) a[i] = sA[kk][ty * 8 + i];
#pragma unroll
      for (int j = 0; j < 8; ++j) b[j] = sB[kk][tx * 8 + j];
#pragma unroll
      for (int i = 0; i < 8; ++i)
#pragma unroll
        for (int j = 0; j < 8; ++j) acc[i][j] = fmaf(a[i], b[j], acc[i][j]);
    }
    __syncthreads();
  }

#pragma unroll
  for (int i = 0; i < 8; ++i) {
    int row = m0 + ty * 8 + i;
    if (row < rows) {
      float sc = rowscale[row];
      float4 v0 = {acc[i][0] * sc, acc[i][1] * sc, acc[i][2] * sc, acc[i][3] * sc};
      float4 v1 = {acc[i][4] * sc, acc[i][5] * sc, acc[i][6] * sc, acc[i][7] * sc};
      float4* p = (float4*)&T[(size_t)row * HID_C + tx * 8];
      p[0] = v0;
      p[1] = v1;
    }
  }
}

// ---------------- aggregation: H[n] = relu(norm_dst[n] * sum_{e: dst=n} T[src[e]] + b) ----------------
__global__ __launch_bounds__(256) void k_agg(
    const float* __restrict__ T, const int* __restrict__ row_start,
    const int* __restrict__ csr_src, const float* __restrict__ norm_dst,
    const float* __restrict__ bias, float* __restrict__ H) {
  int wid = threadIdx.x >> 6, lane = threadIdx.x & 63;
  int n = blockIdx.x * 4 + wid;
  if (n >= N_NODES_C) return;
  int s0 = row_start[n], s1 = row_start[n + 1];
  const float2* T2 = (const float2*)T;
  float ax = 0.f, ay = 0.f;
  for (int base = s0; base < s1; base += 64) {
    int m = s1 - base;
    if (m > 64) m = 64;
    int idx = (lane < m) ? csr_src[base + lane] : 0;
    int j = 0;
    for (; j + 4 <= m; j += 4) {
      int a0 = __shfl(idx, j), a1 = __shfl(idx, j + 1);
      int a2 = __shfl(idx, j + 2), a3 = __shfl(idx, j + 3);
      float2 v0 = T2[(size_t)a0 * 64 + lane];
      float2 v1 = T2[(size_t)a1 * 64 + lane];
      float2 v2 = T2[(size_t)a2 * 64 + lane];
      float2 v3 = T2[(size_t)a3 * 64 + lane];
      ax += v0.x + v1.x + v2.x + v3.x;
      ay += v0.y + v1.y + v2.y + v3.y;
    }
    for (; j < m; ++j) {
      int a = __shfl(idx, j);
      float2 v = T2[(size_t)a * 64 + lane];
      ax += v.x;
      ay += v.y;
    }
  }
  float nd = norm_dst[n];
  float bx = bias[2 * lane], by = bias[2 * lane + 1];
  float2 r;
  r.x = fmaxf(fmaf(ax, nd, bx), 0.f);
  r.y = fmaxf(fmaf(ay, nd, by), 0.f);
  ((float2*)H)[(size_t)n * 64 + lane] = r;
}

// ---------------- fused readout: one block per graph, no atomics ----------------
// w = sigmoid(h.Wv + bv); hg = sum(h*w)/sum(w); out[g] = hg @ Wc + bc
__global__ __launch_bounds__(256) void k_readout(
    const float* __restrict__ H, const float* __restrict__ Wv,
    const float* __restrict__ bv, const int* __restrict__ gstart,
    const float* __restrict__ Wc, const float* __restrict__ bc,
    float* __restrict__ out) {
  int g = blockIdx.x;
  int wid = threadIdx.x >> 6, lane = threadIdx.x & 63;
  int s0 = gstart[g], s1 = gstart[g + 1];
  float2 wv2 = ((const float2*)Wv)[lane];
  float bvs = bv[0];
  float ax = 0.f, ay = 0.f, dw = 0.f;
  for (int n = s0 + wid; n < s1; n += 4) {
    float2 h2 = ((const float2*)H)[(size_t)n * 64 + lane];
    float p = h2.x * wv2.x + h2.y * wv2.y;
#pragma unroll
    for (int off = 32; off > 0; off >>= 1) p += __shfl_xor(p, off);
    float w = 1.f / (1.f + expf(-(p + bvs)));
    ax += h2.x * w;
    ay += h2.y * w;
    dw += w;  // identical across lanes after butterfly
  }
  __shared__ float2 snum[4][64];
  __shared__ float sden[4];
  __shared__ float hg[HID_C];
  snum[wid][lane] = make_float2(ax, ay);
  if (lane == 0) sden[wid] = dw;
  __syncthreads();
  if (wid == 0) {
    float2 a = snum[0][lane], b = snum[1][lane], c = snum[2][lane], d = snum[3][lane];
    float den = sden[0] + sden[1] + sden[2] + sden[3];
    float inv = (den > 0.f) ? 1.f / den : 0.f;
    hg[2 * lane] = (a.x + b.x + c.x + d.x) * inv;
    hg[2 * lane + 1] = (a.y + b.y + c.y + d.y) * inv;
  }
  __syncthreads();
  if (threadIdx.x < NCLS_C) {
    int c = threadIdx.x;
    float acc = 0.f;
    for (int k = 0; k < HID_C; ++k) acc = fmaf(hg[k], Wc[k * NCLS_C + c], acc);
    out[g * NCLS_C + c] = acc + bc[c];
  }
}

extern "C" void kernel_launch(void* const* d_in, const int* in_sizes, int n_in,
                              void* d_out, int out_size, void* d_ws, size_t ws_size,
                              hipStream_t stream) {
  const float* x = (const float*)d_in[0];
  const int* src = (const int*)d_in[1];
  const int* dst = (const int*)d_in[2];
  const int* gid = (const int*)d_in[3];
  const float* W[4] = {(const float*)d_in[4], (const float*)d_in[6],
                       (const float*)d_in[8], (const float*)d_in[10]};
  const float* b[4] = {(const float*)d_in[5], (const float*)d_in[7],
                       (const float*)d_in[9], (const float*)d_in[11]};
  const float* Wv = (const float*)d_in[12];
  const float* bv = (const float*)d_in[13];
  const float* Wc = (const float*)d_in[14];
  const float* bc = (const float*)d_in[15];
  float* out = (float*)d_out;

  char* ws = (char*)d_ws;
  size_t off = 0;
  auto alloc = [&](size_t bytes) -> char* {
    char* p = ws + off;
    off = (off + bytes + 255) & ~(size_t)255;
    return p;
  };
  int* cnt_out = (int*)alloc((size_t)N_NODES_C * 4);
  int* cnt_in = (int*)alloc((size_t)N_NODES_C * 4);
  float* norm_src = (float*)alloc((size_t)N_NODES_C * 4);
  float* norm_dst = (float*)alloc((size_t)N_NODES_C * 4);
  int* row_start = (int*)alloc((size_t)(N_NODES_C + 1) * 4);
  int* cursor = (int*)alloc((size_t)N_NODES_C * 4);
  int* part = (int*)alloc((size_t)SCAN_BLK * 4);
  int* gstart = (int*)alloc((size_t)(NGRAPH_C + 1) * 4);
  int* csr_src = (int*)alloc((size_t)N_EDGES_C * 4);
  float* tbuf = (float*)alloc((size_t)N_NODES_C * HID_C * 4);
  float* hbuf = (float*)alloc((size_t)N_NODES_C * HID_C * 4);
  (void)ws_size;
  (void)in_sizes;
  (void)n_in;
  (void)out_size;

  hipMemsetAsync(cnt_out, 0, (size_t)N_NODES_C * 4, stream);
  hipMemsetAsync(cnt_in, 0, (size_t)N_NODES_C * 4, stream);

  k_count<<<2048, 256, 0, stream>>>(src, dst, cnt_out, cnt_in);
  k_norm<<<(N_NODES_C + 255) / 256, 256, 0, stream>>>(cnt_out, cnt_in, norm_src, norm_dst);
  k_scan1<<<NCHUNK, SCAN_BLK, 0, stream>>>(cnt_in, part);
  k_scan2<<<1, 1, 0, stream>>>(part, row_start);
  k_scan3<<<NCHUNK, SCAN_BLK, 0, stream>>>(cnt_in, part, row_start, cursor);
  k_fill<<<2048, 256, 0, stream>>>(src, dst, cursor, csr_src);
  k_gstart<<<(N_NODES_C + 255) / 256, 256, 0, stream>>>(gid, gstart);

  int gemm_grid = (N_NODES_C + 127) / 128;
  int node_grid = (N_NODES_C + 3) / 4;
  const float* hin = x;
  for (int l = 0; l < 4; ++l) {
    k_gemm_rowscale<<<gemm_grid, 256, 0, stream>>>(hin, W[l], norm_src, tbuf, N_NODES_C);
    k_agg<<<node_grid, 256, 0, stream>>>(tbuf, row_start, csr_src, norm_dst, b[l], hbuf);
    hin = hbuf;
  }

  k_readout<<<NGRAPH_C, 256, 0, stream>>>(hbuf, Wv, bv, gstart, Wc, bc, out);
}

// Round 3
// 922.490 us; speedup vs baseline: 1.3750x; 1.1460x over previous
//
#include <hip/hip_runtime.h>
#include <hip/hip_bf16.h>

#define N_NODES_C 100000
#define N_EDGES_C 1600000
#define HID_C 128
#define NCLS_C 16
#define NGRAPH_C 512
#define SCAN_BLK 1024
#define NCHUNK ((N_NODES_C + SCAN_BLK - 1) / SCAN_BLK)  // 98
#define FILL_PASSES 4
#define FILL_RANGE ((N_NODES_C + FILL_PASSES - 1) / FILL_PASSES)  // 25000

// ---------------- degree count ----------------
__global__ void k_count(const int* __restrict__ src, const int* __restrict__ dst,
                        int* cnt_out, int* cnt_in) {
  int i = blockIdx.x * blockDim.x + threadIdx.x;
  int stride = gridDim.x * blockDim.x;
  for (; i < N_EDGES_C; i += stride) {
    atomicAdd(&cnt_out[src[i]], 1);
    atomicAdd(&cnt_in[dst[i]], 1);
  }
}

__global__ void k_norm(const int* __restrict__ cnt_out, const int* __restrict__ cnt_in,
                       float* norm_src, float* norm_dst) {
  int i = blockIdx.x * blockDim.x + threadIdx.x;
  if (i < N_NODES_C) {
    norm_src[i] = 1.f / sqrtf(fmaxf((float)cnt_out[i], 1.f));
    norm_dst[i] = 1.f / sqrtf(fmaxf((float)cnt_in[i], 1.f));
  }
}

// ---------------- 3-phase exclusive scan of in-degree -> CSR row offsets ----------------
__global__ void k_scan1(const int* __restrict__ cnt, int* part) {
  __shared__ int s[SCAN_BLK];
  int tid = threadIdx.x;
  int i = blockIdx.x * SCAN_BLK + tid;
  s[tid] = (i < N_NODES_C) ? cnt[i] : 0;
  __syncthreads();
  for (int off = SCAN_BLK / 2; off > 0; off >>= 1) {
    if (tid < off) s[tid] += s[tid + off];
    __syncthreads();
  }
  if (tid == 0) part[blockIdx.x] = s[0];
}

__global__ void k_scan2(int* part, int* row_start) {
  if (threadIdx.x == 0 && blockIdx.x == 0) {
    int run = 0;
    for (int i = 0; i < NCHUNK; ++i) { int v = part[i]; part[i] = run; run += v; }
    row_start[N_NODES_C] = run;
  }
}

__global__ void k_scan3(const int* __restrict__ cnt, const int* __restrict__ part,
                        int* row_start, int* cursor) {
  __shared__ int s[SCAN_BLK];
  int tid = threadIdx.x;
  int i = blockIdx.x * SCAN_BLK + tid;
  int x = (i < N_NODES_C) ? cnt[i] : 0;
  s[tid] = x;
  __syncthreads();
  for (int off = 1; off < SCAN_BLK; off <<= 1) {
    int v = (tid >= off) ? s[tid - off] : 0;
    __syncthreads();
    s[tid] += v;
    __syncthreads();
  }
  if (i < N_NODES_C) {
    int excl = part[blockIdx.x] + s[tid] - x;
    row_start[i] = excl;
    cursor[i] = excl;
  }
}

// ---------------- CSR fill: 4 dst-range passes -> csr region per pass is L2-resident ----------------
__global__ void k_fill(const int* __restrict__ src, const int* __restrict__ dst,
                       int* cursor, int* __restrict__ csr_src) {
  int tid0 = blockIdx.x * blockDim.x + threadIdx.x;
  int stride = gridDim.x * blockDim.x;
#pragma unroll 1
  for (int pass = 0; pass < FILL_PASSES; ++pass) {
    int lo = pass * FILL_RANGE;
    int hi = lo + FILL_RANGE;
    for (int i = tid0; i < N_EDGES_C; i += stride) {
      int d = dst[i];
      if (d >= lo && d < hi) {
        int p = atomicAdd(&cursor[d], 1);
        csr_src[p] = src[i];
      }
    }
  }
}

// ---------------- graph boundary offsets from sorted gid ----------------
__global__ void k_gstart(const int* __restrict__ gid, int* __restrict__ gstart) {
  int n = blockIdx.x * blockDim.x + threadIdx.x;
  if (n >= N_NODES_C) return;
  int g = gid[n];
  int gp = (n == 0) ? -1 : gid[n - 1];
  for (int k = gp + 1; k <= g; ++k) gstart[k] = n;
  if (n == N_NODES_C - 1) {
    for (int k = g + 1; k <= NGRAPH_C; ++k) gstart[k] = N_NODES_C;
  }
}

// ---------------- GEMM: T[m][c] = (sum_k A[m][k] W[k][c]) * rowscale[m] ----------------
// f32 vector GEMM (no fp32 MFMA on CDNA4). 256 thr, tile 128x128, 8x8 micro-tile.
__global__ __launch_bounds__(256) void k_gemm_rowscale(
    const float* __restrict__ A, const float* __restrict__ W,
    const float* __restrict__ rowscale, float* __restrict__ T, int rows) {
  __shared__ float sA[32][132];  // [k][m], pad 4 keeps rows 16B-aligned (132*4=528)
  __shared__ float sB[32][132];  // [k][n]
  int t = threadIdx.x;
  int tx = t & 15, ty = t >> 4;
  int m0 = blockIdx.x * 128;

  float acc[8][8];
#pragma unroll
  for (int i = 0; i < 8; ++i)
#pragma unroll
    for (int j = 0; j < 8; ++j) acc[i][j] = 0.f;

  int ar = t >> 3;          // 0..31 (row base for A staging)
  int ac = (t & 7) * 4;     // col group of 4
  int wk = t >> 5;          // 0..7 (k base for W staging)
  int wn = (t & 31) * 4;    // col group of 4

  for (int k0 = 0; k0 < HID_C; k0 += 32) {
    // stage A chunk: 128 rows x 32 k, float4 loads, transposed into LDS
#pragma unroll
    for (int rr = 0; rr < 4; ++rr) {
      int r = rr * 32 + ar;
      int row = m0 + r;
      float4 v = make_float4(0.f, 0.f, 0.f, 0.f);
      if (row < rows) v = *(const float4*)&A[(size_t)row * HID_C + k0 + ac];
      sA[ac + 0][r] = v.x;
      sA[ac + 1][r] = v.y;
      sA[ac + 2][r] = v.z;
      sA[ac + 3][r] = v.w;
    }
    // stage W chunk: 32 k x 128 n, float4 load + float4 LDS store
#pragma unroll
    for (int i = 0; i < 4; ++i) {
      int kc = i * 8 + wk;
      float4 v = *(const float4*)&W[(size_t)(k0 + kc) * HID_C + wn];
      *(float4*)&sB[kc][wn] = v;
    }
    __syncthreads();

#pragma unroll 8
    for (int kk = 0; kk < 32; ++kk) {
      float a[8], b[8];
#pragma unroll
      for (int i = 0; i < 8; ++i) a[i] = sA[kk][ty * 8 + i];
#pragma unroll
      for (int j = 0; j < 8; ++j) b[j] = sB[kk][tx * 8 + j];
#pragma unroll
      for (int i = 0; i < 8; ++i)
#pragma unroll
        for (int j = 0; j < 8; ++j) acc[i][j] = fmaf(a[i], b[j], acc[i][j]);
    }
    __syncthreads();
  }

#pragma unroll
  for (int i = 0; i < 8; ++i) {
    int row = m0 + ty * 8 + i;
    if (row < rows) {
      float sc = rowscale[row];
      float4 v0 = {acc[i][0] * sc, acc[i][1] * sc, acc[i][2] * sc, acc[i][3] * sc};
      float4 v1 = {acc[i][4] * sc, acc[i][5] * sc, acc[i][6] * sc, acc[i][7] * sc};
      float4* p = (float4*)&T[(size_t)row * HID_C + tx * 8];
      p[0] = v0;
      p[1] = v1;
    }
  }
}

// ---------------- aggregation: H[n] = relu(norm_dst[n] * sum_{e: dst=n} T[src[e]] + b) ----------------
// One wave per node. csr_src read once per edge at a wave-uniform address (one line,
// vmem-pipelined); 8-deep unroll gives 8 independent row-load chains in flight.
__global__ __launch_bounds__(256) void k_agg(
    const float* __restrict__ T, const int* __restrict__ row_start,
    const int* __restrict__ csr_src, const float* __restrict__ norm_dst,
    const float* __restrict__ bias, float* __restrict__ H) {
  int wid = threadIdx.x >> 6, lane = threadIdx.x & 63;
  int n = blockIdx.x * 4 + wid;
  if (n >= N_NODES_C) return;
  int s0 = row_start[n], s1 = row_start[n + 1];
  const float2* T2 = (const float2*)T;
  float ax = 0.f, ay = 0.f;
  int e = s0;
  for (; e + 8 <= s1; e += 8) {
    int a0 = csr_src[e + 0], a1 = csr_src[e + 1];
    int a2 = csr_src[e + 2], a3 = csr_src[e + 3];
    int a4 = csr_src[e + 4], a5 = csr_src[e + 5];
    int a6 = csr_src[e + 6], a7 = csr_src[e + 7];
    float2 v0 = T2[(size_t)a0 * 64 + lane];
    float2 v1 = T2[(size_t)a1 * 64 + lane];
    float2 v2 = T2[(size_t)a2 * 64 + lane];
    float2 v3 = T2[(size_t)a3 * 64 + lane];
    float2 v4 = T2[(size_t)a4 * 64 + lane];
    float2 v5 = T2[(size_t)a5 * 64 + lane];
    float2 v6 = T2[(size_t)a6 * 64 + lane];
    float2 v7 = T2[(size_t)a7 * 64 + lane];
    ax += v0.x + v1.x + v2.x + v3.x + v4.x + v5.x + v6.x + v7.x;
    ay += v0.y + v1.y + v2.y + v3.y + v4.y + v5.y + v6.y + v7.y;
  }
  for (; e < s1; ++e) {
    int a = csr_src[e];
    float2 v = T2[(size_t)a * 64 + lane];
    ax += v.x;
    ay += v.y;
  }
  float nd = norm_dst[n];
  float bx = bias[2 * lane], by = bias[2 * lane + 1];
  float2 r;
  r.x = fmaxf(fmaf(ax, nd, bx), 0.f);
  r.y = fmaxf(fmaf(ay, nd, by), 0.f);
  ((float2*)H)[(size_t)n * 64 + lane] = r;
}

// ---------------- fused readout: one block per graph, no atomics ----------------
__global__ __launch_bounds__(256) void k_readout(
    const float* __restrict__ H, const float* __restrict__ Wv,
    const float* __restrict__ bv, const int* __restrict__ gstart,
    const float* __restrict__ Wc, const float* __restrict__ bc,
    float* __restrict__ out) {
  int g = blockIdx.x;
  int wid = threadIdx.x >> 6, lane = threadIdx.x & 63;
  int s0 = gstart[g], s1 = gstart[g + 1];
  float2 wv2 = ((const float2*)Wv)[lane];
  float bvs = bv[0];
  float ax = 0.f, ay = 0.f, dw = 0.f;
  for (int n = s0 + wid; n < s1; n += 4) {
    float2 h2 = ((const float2*)H)[(size_t)n * 64 + lane];
    float p = h2.x * wv2.x + h2.y * wv2.y;
#pragma unroll
    for (int off = 32; off > 0; off >>= 1) p += __shfl_xor(p, off);
    float w = 1.f / (1.f + expf(-(p + bvs)));
    ax += h2.x * w;
    ay += h2.y * w;
    dw += w;  // identical across lanes after butterfly
  }
  __shared__ float2 snum[4][64];
  __shared__ float sden[4];
  __shared__ float hg[HID_C];
  snum[wid][lane] = make_float2(ax, ay);
  if (lane == 0) sden[wid] = dw;
  __syncthreads();
  if (wid == 0) {
    float2 a = snum[0][lane], b = snum[1][lane], c = snum[2][lane], d = snum[3][lane];
    float den = sden[0] + sden[1] + sden[2] + sden[3];
    float inv = (den > 0.f) ? 1.f / den : 0.f;
    hg[2 * lane] = (a.x + b.x + c.x + d.x) * inv;
    hg[2 * lane + 1] = (a.y + b.y + c.y + d.y) * inv;
  }
  __syncthreads();
  if (threadIdx.x < NCLS_C) {
    int c = threadIdx.x;
    float acc = 0.f;
    for (int k = 0; k < HID_C; ++k) acc = fmaf(hg[k], Wc[k * NCLS_C + c], acc);
    out[g * NCLS_C + c] = acc + bc[c];
  }
}

extern "C" void kernel_launch(void* const* d_in, const int* in_sizes, int n_in,
                              void* d_out, int out_size, void* d_ws, size_t ws_size,
                              hipStream_t stream) {
  const float* x = (const float*)d_in[0];
  const int* src = (const int*)d_in[1];
  const int* dst = (const int*)d_in[2];
  const int* gid = (const int*)d_in[3];
  const float* W[4] = {(const float*)d_in[4], (const float*)d_in[6],
                       (const float*)d_in[8], (const float*)d_in[10]};
  const float* b[4] = {(const float*)d_in[5], (const float*)d_in[7],
                       (const float*)d_in[9], (const float*)d_in[11]};
  const float* Wv = (const float*)d_in[12];
  const float* bv = (const float*)d_in[13];
  const float* Wc = (const float*)d_in[14];
  const float* bc = (const float*)d_in[15];
  float* out = (float*)d_out;

  char* ws = (char*)d_ws;
  size_t off = 0;
  auto alloc = [&](size_t bytes) -> char* {
    char* p = ws + off;
    off = (off + bytes + 255) & ~(size_t)255;
    return p;
  };
  int* cnt_out = (int*)alloc((size_t)N_NODES_C * 4);
  int* cnt_in = (int*)alloc((size_t)N_NODES_C * 4);
  float* norm_src = (float*)alloc((size_t)N_NODES_C * 4);
  float* norm_dst = (float*)alloc((size_t)N_NODES_C * 4);
  int* row_start = (int*)alloc((size_t)(N_NODES_C + 1) * 4);
  int* cursor = (int*)alloc((size_t)N_NODES_C * 4);
  int* part = (int*)alloc((size_t)SCAN_BLK * 4);
  int* gstart = (int*)alloc((size_t)(NGRAPH_C + 1) * 4);
  int* csr_src = (int*)alloc((size_t)N_EDGES_C * 4);
  float* tbuf = (float*)alloc((size_t)N_NODES_C * HID_C * 4);
  float* hbuf = (float*)alloc((size_t)N_NODES_C * HID_C * 4);
  (void)ws_size;
  (void)in_sizes;
  (void)n_in;
  (void)out_size;

  hipMemsetAsync(cnt_out, 0, (size_t)N_NODES_C * 4, stream);
  hipMemsetAsync(cnt_in, 0, (size_t)N_NODES_C * 4, stream);

  k_count<<<2048, 256, 0, stream>>>(src, dst, cnt_out, cnt_in);
  k_norm<<<(N_NODES_C + 255) / 256, 256, 0, stream>>>(cnt_out, cnt_in, norm_src, norm_dst);
  k_scan1<<<NCHUNK, SCAN_BLK, 0, stream>>>(cnt_in, part);
  k_scan2<<<1, 1, 0, stream>>>(part, row_start);
  k_scan3<<<NCHUNK, SCAN_BLK, 0, stream>>>(cnt_in, part, row_start, cursor);
  k_fill<<<2048, 256, 0, stream>>>(src, dst, cursor, csr_src);
  k_gstart<<<(N_NODES_C + 255) / 256, 256, 0, stream>>>(gid, gstart);

  int gemm_grid = (N_NODES_C + 127) / 128;
  int node_grid = (N_NODES_C + 3) / 4;
  const float* hin = x;
  for (int l = 0; l < 4; ++l) {
    k_gemm_rowscale<<<gemm_grid, 256, 0, stream>>>(hin, W[l], norm_src, tbuf, N_NODES_C);
    k_agg<<<node_grid, 256, 0, stream>>>(tbuf, row_start, csr_src, norm_dst, b[l], hbuf);
    hin = hbuf;
  }

  k_readout<<<NGRAPH_C, 256, 0, stream>>>(hbuf, Wv, bv, gstart, Wc, bc, out);
}